// Round 21
// baseline (274.108 us; speedup 1.0000x reference)
//
#include <hip/hip_runtime.h>
#include <hip/hip_bf16.h>

#define NT 8192   // total nodes (2 graphs)
#define NN 4096   // nodes per graph
#define CD 128    // channels
#define NE 65536  // edges per graph

typedef __attribute__((ext_vector_type(8))) short bf16x8;
typedef __attribute__((ext_vector_type(16))) float f32x16;
typedef __attribute__((ext_vector_type(4))) float f32x4;

// ---------------- prep: concat + weight transposes + attention params + DEG zero ----------------
__global__ __launch_bounds__(256) void k_prep(
    const float* __restrict__ x1, const float* __restrict__ x2, float* __restrict__ X,
    const float* __restrict__ W1, const float* __restrict__ W2, const float* __restrict__ WL,
    float* __restrict__ WT1, float* __restrict__ WT2, float* __restrict__ WTL,
    const float* __restrict__ wlw0, const float* __restrict__ wlb0,
    const float* __restrict__ wrw0, const float* __restrict__ wrb0,
    const float* __restrict__ al0, const float* __restrict__ ar0,
    const float* __restrict__ wlw1, const float* __restrict__ wlb1,
    const float* __restrict__ wrw1, const float* __restrict__ wrb1,
    const float* __restrict__ al1, const float* __restrict__ ar1,
    float* __restrict__ VP, int* __restrict__ DEG) {
  int b = blockIdx.x, tid = threadIdx.x;
  int gid = b * 256 + tid;  // 0..131071
  {
    const f32x4* s1 = (const f32x4*)x1;
    const f32x4* s2 = (const f32x4*)x2;
    f32x4* d = (f32x4*)X;
    d[gid] = s1[gid];
    d[gid + NN * CD / 4] = s2[gid];
  }
  if (gid < 81920) {
    int idx = gid;
    if (idx < 32768) { int c = idx >> 8, k = idx & 255; WT1[k * 128 + c] = W1[idx]; }
    else if (idx < 65536) { int j = idx - 32768; int c = j >> 8, k = j & 255; WT2[k * 128 + c] = W2[j]; }
    else { int j = idx - 65536; int c = j >> 7, k = j & 127; WTL[k * 128 + c] = WL[j]; }
  }
  if ((b == 508 || b == 509) && tid < 128) {
    int L = b - 508;
    const float* wlw = L ? wlw1 : wlw0;
    const float* wlb = L ? wlb1 : wlb0;
    const float* wrw = L ? wrw1 : wrw0;
    const float* wrb = L ? wrb1 : wrb0;
    const float* alv = L ? al1 : al0;
    const float* arv = L ? ar1 : ar0;
    float* vp = VP + L * 258;
    int c = tid;
    float sl = 0.f, sr = 0.f;
    for (int h = 0; h < 128; ++h) {
      sl += wlw[h * 128 + c] * alv[h];
      sr += wrw[h * 128 + c] * arv[h];
    }
    vp[c] = sl;
    vp[128 + c] = sr;
    if (c < 2) {
      const float* bb = c ? wrb : wlb;
      const float* aa = c ? arv : alv;
      float s = 0.f;
      for (int h = 0; h < 128; ++h) s += bb[h] * aa[h];
      vp[256 + c] = s;
    }
  }
  if (gid < 2 * NN) DEG[gid] = 0;
}

// ---------------- shared bodies ----------------
__device__ inline void alar_row(const float* __restrict__ X, const float* __restrict__ VP,
                                float* __restrict__ AL, float* __restrict__ AR,
                                int row, int lane) {
  float x0 = X[row * 128 + lane], x1 = X[row * 128 + 64 + lane];
  float sl = x0 * VP[lane] + x1 * VP[64 + lane];
  float sr = x0 * VP[128 + lane] + x1 * VP[192 + lane];
  #pragma unroll
  for (int m = 1; m < 64; m <<= 1) {
    sl += __shfl_xor(sl, m, 64);
    sr += __shfl_xor(sr, m, 64);
  }
  if (lane == 0) { AL[row] = sl + VP[256]; AR[row] = sr + VP[257]; }
}

__device__ void rank_body(int rb, int tid, const float* __restrict__ AR,
                          int* __restrict__ RANK) {
  __shared__ float tile[1024];
  int jb = rb & 31, tb = rb >> 5;
  int base = tb * 1024;
  for (int t = tid; t < 1024; t += 256) tile[t] = AR[base + t];
  __syncthreads();
  int j = jb * 256 + tid;
  float aj = AR[j];
  int cnt = 0;
  #pragma unroll 8
  for (int u = 0; u < 1024; ++u) {
    float a2 = tile[u];
    cnt += (a2 < aj || (a2 == aj && (base + u) < j)) ? 1 : 0;
  }
  atomicAdd(&RANK[j], cnt);
}

__device__ void scanoff_body(int g, int tid, const int* __restrict__ DEG,
                             int* __restrict__ OFFS, int* __restrict__ CURS) {
  __shared__ int part[256];
  int loc[16];
  int s = 0;
  #pragma unroll
  for (int i = 0; i < 16; ++i) { loc[i] = s; s += DEG[g * NN + tid * 16 + i]; }
  part[tid] = s;
  __syncthreads();
  for (int d = 1; d < 256; d <<= 1) {
    int v = part[tid];
    int o = (tid >= d) ? part[tid - d] : 0;
    __syncthreads();
    part[tid] = v + o;
    __syncthreads();
  }
  int excl = tid ? part[tid - 1] : 0;
  #pragma unroll
  for (int i = 0; i < 16; ++i) {
    int o = excl + loc[i];
    OFFS[g * (NN + 1) + tid * 16 + i] = o;
    CURS[g * NN + tid * 16 + i] = o;
  }
  if (tid == 255) OFFS[g * (NN + 1) + NN] = part[255];
}

// ---------------- s2: deg atomics || alar0 (+RANK zero) ----------------
__global__ __launch_bounds__(256) void k_s2(
    const int* __restrict__ EI1, const int* __restrict__ EI2, int* __restrict__ DEG,
    const float* __restrict__ X, const float* __restrict__ VP0,
    float* __restrict__ AL, float* __restrict__ AR, int* __restrict__ RANK) {
  int b = blockIdx.x, tid = threadIdx.x;
  if (b < 512) {
    int gid = b * 256 + tid;
    int g = gid >> 16, e = gid & 65535;
    const int* src = g ? EI2 : EI1;
    atomicAdd(&DEG[g * NN + src[e]], 1);
  } else {
    int bb = b - 512;
    if (bb < 32) RANK[bb * 256 + tid] = 0;
    alar_row(X, VP0, AL, AR, bb * 4 + (tid >> 6), tid & 63);
  }
}

// ---------------- s3: scanoff || rank0 ----------------
__global__ __launch_bounds__(256) void k_s3(
    const int* __restrict__ DEG, int* __restrict__ OFFS, int* __restrict__ CURS,
    const float* __restrict__ AR, int* __restrict__ RANK) {
  int b = blockIdx.x, tid = threadIdx.x;
  if (b < 2) scanoff_body(b, tid, DEG, OFFS, CURS);
  else rank_body(b - 2, tid, AR, RANK);
}

// ---------------- s4: fill || perm0 ----------------
__global__ __launch_bounds__(256) void k_s4(
    const int* __restrict__ EI1, const int* __restrict__ EI2,
    int* __restrict__ CURS, int* __restrict__ ADJ,
    const int* __restrict__ RANK, const float* __restrict__ AR,
    int* __restrict__ PERM, float* __restrict__ ARS) {
  int b = blockIdx.x, tid = threadIdx.x;
  if (b < 512) {
    int gid = b * 256 + tid;
    int g = gid >> 16, e = gid & 65535;
    const int* ei = g ? EI2 : EI1;
    int s = ei[e], d = ei[NE + e];
    int pos = atomicAdd(&CURS[g * NN + s], 1);
    ADJ[g * NE + pos] = d;
  } else {
    int j = (b - 512) * 256 + tid;
    int r = RANK[j];
    PERM[r] = j;
    ARS[r] = AR[j];
  }
}

// plain rank (layer 1) and perm (layer 1)
__global__ void k_rank(const float* __restrict__ AR, int* __restrict__ RANK) {
  rank_body(blockIdx.x, threadIdx.x, AR, RANK);
}
__global__ void k_perm(const int* __restrict__ RANK, const float* __restrict__ AR,
                       int* __restrict__ PERM, float* __restrict__ ARS) {
  int j = blockIdx.x * 256 + threadIdx.x;
  int r = RANK[j];
  PERM[r] = j;
  ARS[r] = AR[j];
}

// hierarchical prefix sums, 4-way t-split (512 blocks); blocks<32 zero RANK for next rank pass
__global__ __launch_bounds__(256) void k_scanA(
    const float* __restrict__ X, const int* __restrict__ PERM,
    const float* __restrict__ ARS, int* __restrict__ RANK,
    float* __restrict__ P1, float* __restrict__ P2,
    float* __restrict__ CT1, float* __restrict__ CT2,
    float* __restrict__ Q1L, float* __restrict__ Q2L,
    float* __restrict__ QCT1, float* __restrict__ QCT2) {
  __shared__ int pc[64];
  __shared__ float w[2][64];
  __shared__ float part[2][4][32];
  __shared__ float qpart[2][4];
  int b = blockIdx.x;
  if (b < 32) RANK[b * 256 + threadIdx.x] = 0;
  int chunk = b >> 2, sub = b & 3;
  int tid = threadIdx.x;
  int a = tid >> 7;
  int g = (tid >> 5) & 3;
  int cl = tid & 31;
  int c = sub * 32 + cl;
  if (tid < 64) {
    int r = chunk * 64 + tid;
    pc[tid] = PERM[r];
    float ar = ARS[r];
    w[0][tid] = __expf(ar);
    w[1][tid] = __expf(0.2f * ar);
  }
  __syncthreads();
  int t0 = g * 16;
  float loc[16];
  float acc = 0.f;
  #pragma unroll 4
  for (int t = 0; t < 16; ++t) {
    acc += w[a][t0 + t] * X[pc[t0 + t] * 128 + c];
    loc[t] = acc;
  }
  part[a][g][cl] = acc;
  float qloc[16];
  float qacc = 0.f;
  bool doQ = (sub == 0 && cl == 0);
  if (doQ) {
    for (int t = 0; t < 16; ++t) { qacc += w[a][t0 + t]; qloc[t] = qacc; }
    qpart[a][g] = qacc;
  }
  __syncthreads();
  float off = (g > 0 ? part[a][0][cl] : 0.f) + (g > 1 ? part[a][1][cl] : 0.f) +
              (g > 2 ? part[a][2][cl] : 0.f);
  float* P = a ? P2 : P1;
  #pragma unroll 4
  for (int t = 0; t < 16; ++t) P[(chunk * 64 + t0 + t) * 128 + c] = loc[t] + off;
  if (g == 3) (a ? CT2 : CT1)[chunk * 128 + c] = off + acc;
  if (doQ) {
    float qoff = (g > 0 ? qpart[a][0] : 0.f) + (g > 1 ? qpart[a][1] : 0.f) +
                 (g > 2 ? qpart[a][2] : 0.f);
    float* Q = a ? Q2L : Q1L;
    for (int t = 0; t < 16; ++t) Q[chunk * 64 + t0 + t] = qloc[t] + qoff;
    if (g == 3) (a ? QCT2 : QCT1)[chunk] = qoff + qacc;
  }
}

__global__ __launch_bounds__(320) void k_scanB(
    const float* __restrict__ CT1, const float* __restrict__ CT2,
    const float* __restrict__ QCT1, const float* __restrict__ QCT2,
    float* __restrict__ OFF1, float* __restrict__ OFF2,
    float* __restrict__ QOF1, float* __restrict__ QOF2) {
  int tid = threadIdx.x;
  if (tid < 128) {
    float acc = 0.f;
    #pragma unroll 8
    for (int ch = 0; ch < 128; ++ch) { acc += CT1[ch * 128 + tid]; OFF1[ch * 128 + tid] = acc; }
  } else if (tid < 256) {
    int c = tid - 128;
    float acc = 0.f;
    #pragma unroll 8
    for (int ch = 0; ch < 128; ++ch) { acc += CT2[ch * 128 + c]; OFF2[ch * 128 + c] = acc; }
  } else if (tid == 256) {
    float acc = 0.f;
    for (int ch = 0; ch < 128; ++ch) { acc += QCT1[ch]; QOF1[ch] = acc; }
  } else if (tid == 257) {
    float acc = 0.f;
    for (int ch = 0; ch < 128; ++ch) { acc += QCT2[ch]; QOF2[ch] = acc; }
  }
}

// ot[i] = x[i] - (A1*suffix1 + A2*prefix2)/(A1*qsuf1 + A2*qpre2)
__global__ void k_combine(const float* __restrict__ X, const float* __restrict__ AL,
                          const float* __restrict__ ARS,
                          const float* __restrict__ P1, const float* __restrict__ P2,
                          const float* __restrict__ OFF1, const float* __restrict__ OFF2,
                          const float* __restrict__ Q1L, const float* __restrict__ Q2L,
                          const float* __restrict__ QOF1, const float* __restrict__ QOF2,
                          float* __restrict__ OT) {
  int row = blockIdx.x * 2 + (threadIdx.x >> 7);
  int c = threadIdx.x & 127;
  float ali = AL[row];
  float A1 = __expf(ali), A2 = __expf(0.2f * ali);
  float xv = -ali;
  int lo = 0, hi = NT;
  while (lo < hi) {
    int mid = (lo + hi) >> 1;
    if (ARS[mid] <= xv) lo = mid + 1; else hi = mid;
  }
  int b = lo - 1;
  float p1 = 0.f, p2 = 0.f, q1 = 0.f, q2 = 0.f;
  if (b >= 0) {
    int ch = b >> 6;
    p1 = P1[b * 128 + c] + (ch ? OFF1[(ch - 1) * 128 + c] : 0.f);
    p2 = P2[b * 128 + c] + (ch ? OFF2[(ch - 1) * 128 + c] : 0.f);
    q1 = Q1L[b] + (ch ? QOF1[ch - 1] : 0.f);
    q2 = Q2L[b] + (ch ? QOF2[ch - 1] : 0.f);
  }
  float T1 = OFF1[127 * 128 + c];
  float QT1 = QOF1[127];
  float num = A1 * (T1 - p1) + A2 * p2;
  float den = A1 * (QT1 - q1) + A2 * q2;
  OT[row * 128 + c] = X[row * 128 + c] - num / den;
}

// ---------------- fused: CSR-mean gather (LDS indices, prefetch-pipelined) + relu + GEMM ----------------
__global__ __launch_bounds__(256, 4) void k_ag(
    const float* __restrict__ X, const float* __restrict__ OT,
    const int* __restrict__ OFFS, const int* __restrict__ ADJ,
    const float* __restrict__ WT, const float* __restrict__ WB, float* __restrict__ XN,
    int mode,  // 0: + alar(next layer) ; 1: + lin -> FBF
    const float* __restrict__ VP1, float* __restrict__ AL, float* __restrict__ AR,
    const float* __restrict__ WTL, const float* __restrict__ LINB,
    __hip_bfloat16* __restrict__ FBF) {
  __shared__ float sA[8 * 256];
  __shared__ float sB[8 * 128];
  __shared__ int sOff[9];
  __shared__ int sIdx[1024];
  int b = blockIdx.x, tid = threadIdx.x;
  int lane = tid & 63, wv = tid >> 6, c4 = lane & 31;
  int g = b >> 9;
  int n0 = (b * 8) & (NN - 1);
  if (tid < 9) sOff[tid] = OFFS[g * (NN + 1) + n0 + tid];
  __syncthreads();
  int begAll = sOff[0], cnt = sOff[8] - begAll;
  const int* adjg = ADJ + g * NE + begAll;
  for (int t = tid; t < cnt; t += 256) sIdx[t] = adjg[t];
  __syncthreads();
  {
    const f32x4* src = (const f32x4*)((lane < 32 ? X : OT) + (size_t)g * NN * CD);
    #pragma unroll
    for (int k = 0; k < 2; ++k) {
      int ln = wv * 2 + k;
      int e0 = sOff[ln] - begAll, e1 = sOff[ln + 1] - begAll;
      f32x4 p0 = src[(n0 + ln) * 32 + c4];   // self loop
      f32x4 p1 = {0.f, 0.f, 0.f, 0.f}, p2 = p1, p3 = p1;
      // double-buffered prefetch: ~8 row loads in flight (clamped idx, masked accumulate)
      f32x4 b0 = src[sIdx[(e0 + 0) < e1 ? e0 + 0 : e0] * 32 + c4];
      f32x4 b1 = src[sIdx[(e0 + 1) < e1 ? e0 + 1 : e0] * 32 + c4];
      f32x4 b2 = src[sIdx[(e0 + 2) < e1 ? e0 + 2 : e0] * 32 + c4];
      f32x4 b3 = src[sIdx[(e0 + 3) < e1 ? e0 + 3 : e0] * 32 + c4];
      for (int j = e0; j < e1; j += 4) {
        f32x4 c0 = b0, c1 = b1, c2 = b2, c3 = b3;
        int m0 = (j + 4) < e1 ? j + 4 : e0;
        int m1 = (j + 5) < e1 ? j + 5 : e0;
        int m2 = (j + 6) < e1 ? j + 6 : e0;
        int m3 = (j + 7) < e1 ? j + 7 : e0;
        b0 = src[sIdx[m0] * 32 + c4];
        b1 = src[sIdx[m1] * 32 + c4];
        b2 = src[sIdx[m2] * 32 + c4];
        b3 = src[sIdx[m3] * 32 + c4];
        p0 += c0;                       // j < e1 always
        if (j + 1 < e1) p1 += c1;
        if (j + 2 < e1) p2 += c2;
        if (j + 3 < e1) p3 += c3;
      }
      f32x4 r = (p0 + p1) + (p2 + p3);
      r /= (float)(e1 - e0 + 1);
      #pragma unroll
      for (int q = 0; q < 4; ++q) r[q] = fmaxf(r[q], 0.f);
      *(f32x4*)&sA[ln * 256 + (lane < 32 ? c4 * 4 : 128 + c4 * 4)] = r;
    }
  }
  __syncthreads();
  int c = tid & 127, half = tid >> 7;
  float accv[4];
  float bc = WB[c];
  #pragma unroll
  for (int i = 0; i < 4; ++i) accv[i] = bc;
  for (int k4 = 0; k4 < 64; ++k4) {
    float w0 = WT[(k4 * 4 + 0) * 128 + c];
    float w1v = WT[(k4 * 4 + 1) * 128 + c];
    float w2v = WT[(k4 * 4 + 2) * 128 + c];
    float w3 = WT[(k4 * 4 + 3) * 128 + c];
    #pragma unroll
    for (int i = 0; i < 4; ++i) {
      f32x4 av = *(const f32x4*)&sA[(half * 4 + i) * 256 + k4 * 4];
      accv[i] += av[0] * w0 + av[1] * w1v + av[2] * w2v + av[3] * w3;
    }
  }
  #pragma unroll
  for (int i = 0; i < 4; ++i) {
    sB[(half * 4 + i) * 128 + c] = accv[i];
    if (mode == 0) XN[(size_t)(b * 8 + half * 4 + i) * 128 + c] = accv[i];
  }
  __syncthreads();
  if (mode == 0) {
    #pragma unroll
    for (int k = 0; k < 2; ++k) {
      int lr = wv * 2 + k;
      float x0 = sB[lr * 128 + lane], x1 = sB[lr * 128 + 64 + lane];
      float sl = x0 * VP1[lane] + x1 * VP1[64 + lane];
      float sr = x0 * VP1[128 + lane] + x1 * VP1[192 + lane];
      #pragma unroll
      for (int m = 1; m < 64; m <<= 1) {
        sl += __shfl_xor(sl, m, 64);
        sr += __shfl_xor(sr, m, 64);
      }
      if (lane == 0) { AL[b * 8 + lr] = sl + VP1[256]; AR[b * 8 + lr] = sr + VP1[257]; }
    }
  } else {
    float acl[4];
    float lb = LINB[c];
    #pragma unroll
    for (int i = 0; i < 4; ++i) acl[i] = lb;
    for (int k4 = 0; k4 < 32; ++k4) {
      float w0 = WTL[(k4 * 4 + 0) * 128 + c];
      float w1v = WTL[(k4 * 4 + 1) * 128 + c];
      float w2v = WTL[(k4 * 4 + 2) * 128 + c];
      float w3 = WTL[(k4 * 4 + 3) * 128 + c];
      #pragma unroll
      for (int i = 0; i < 4; ++i) {
        f32x4 av = *(const f32x4*)&sB[(half * 4 + i) * 128 + k4 * 4];
        acl[i] += av[0] * w0 + av[1] * w1v + av[2] * w2v + av[3] * w3;
      }
    }
    #pragma unroll
    for (int i = 0; i < 4; ++i)
      FBF[(size_t)(b * 8 + half * 4 + i) * 128 + c] = __float2bfloat16(acl[i]);
  }
}

// ---------------- final: out = sigmoid(F F^T), F bf16 8192x128 ----------------
__device__ inline f32x16 zero16() {
  f32x16 v;
  #pragma unroll
  for (int i = 0; i < 16; ++i) v[i] = 0.f;
  return v;
}

__device__ inline float sigf(float v) {
  return __builtin_amdgcn_rcpf(1.f + __expf(-v));
}

__global__ __launch_bounds__(256) void k_final(const unsigned short* __restrict__ F,
                                               float* __restrict__ out) {
  __shared__ __align__(16) char smem[65536];
  unsigned short* AT = (unsigned short*)smem;
  unsigned short* BT = AT + 16384;
  int cb = blockIdx.x, rb = blockIdx.y;
  int tid = threadIdx.x;
  #pragma unroll
  for (int q = 0; q < 8; ++q) {
    int idx = q * 256 + tid;
    int r = idx >> 4, ck = idx & 15;
    unsigned off = (unsigned)((r * 256 + ck * 16) ^ ((r & 7) << 4));
    uint4 va = *(const uint4*)(F + (size_t)(rb * 128 + r) * 128 + ck * 8);
    *(uint4*)((char*)AT + off) = va;
    uint4 vb = *(const uint4*)(F + (size_t)(cb * 128 + r) * 128 + ck * 8);
    *(uint4*)((char*)BT + off) = vb;
  }
  __syncthreads();
  int lane = tid & 63, w = tid >> 6;
  int wr = w >> 1, wc = w & 1;
  int l31 = lane & 31, kh = lane >> 5;
  int xorm = (l31 & 7) << 4;
  int rowA0 = wr * 64 + l31, rowA1 = rowA0 + 32;
  int rowB0 = wc * 64 + l31, rowB1 = rowB0 + 32;
  f32x16 a00 = zero16(), a01 = zero16(), a10 = zero16(), a11 = zero16();
  #pragma unroll
  for (int ks = 0; ks < 8; ++ks) {
    int kb = ks * 32 + kh * 16;
    bf16x8 av0 = *(const bf16x8*)((const char*)AT + ((rowA0 * 256 + kb) ^ xorm));
    bf16x8 av1 = *(const bf16x8*)((const char*)AT + ((rowA1 * 256 + kb) ^ xorm));
    bf16x8 bv0 = *(const bf16x8*)((const char*)BT + ((rowB0 * 256 + kb) ^ xorm));
    bf16x8 bv1 = *(const bf16x8*)((const char*)BT + ((rowB1 * 256 + kb) ^ xorm));
    a00 = __builtin_amdgcn_mfma_f32_32x32x16_bf16(av0, bv0, a00, 0, 0, 0);
    a01 = __builtin_amdgcn_mfma_f32_32x32x16_bf16(av0, bv1, a01, 0, 0, 0);
    a10 = __builtin_amdgcn_mfma_f32_32x32x16_bf16(av1, bv0, a10, 0, 0, 0);
    a11 = __builtin_amdgcn_mfma_f32_32x32x16_bf16(av1, bv1, a11, 0, 0, 0);
  }
  __syncthreads();
  float* lw = (float*)smem + w * 4096;
  #pragma unroll
  for (int r = 0; r < 16; ++r) {
    int rl = (r & 3) + 8 * (r >> 2) + 4 * kh;
    lw[rl * 64 + l31] = sigf(a00[r]);
    lw[rl * 64 + l31 + 32] = sigf(a01[r]);
    lw[(rl + 32) * 64 + l31] = sigf(a10[r]);
    lw[(rl + 32) * 64 + l31 + 32] = sigf(a11[r]);
  }
  int grb = rb * 128 + wr * 64, gcb = cb * 128 + wc * 64;
  #pragma unroll
  for (int j = 0; j < 16; ++j) {
    int row = j * 4 + (lane >> 4);
    int c4 = (lane & 15) * 4;
    f32x4 v = *(const f32x4*)&lw[row * 64 + c4];
    *(f32x4*)&out[(size_t)(grb + row) * 8192 + gcb + c4] = v;
  }
}

// ---------------- host ----------------
extern "C" void kernel_launch(void* const* d_in, const int* in_sizes, int n_in,
                              void* d_out, int out_size, void* d_ws, size_t ws_size,
                              hipStream_t stream) {
  (void)in_sizes; (void)n_in; (void)out_size; (void)ws_size;
  const float* x1 = (const float*)d_in[0];
  const float* x2 = (const float*)d_in[1];
  const int* ei1 = (const int*)d_in[2];
  const int* ei2 = (const int*)d_in[3];
  const float* wl_w[2] = {(const float*)d_in[4], (const float*)d_in[10]};
  const float* wl_b[2] = {(const float*)d_in[5], (const float*)d_in[11]};
  const float* wr_w[2] = {(const float*)d_in[6], (const float*)d_in[12]};
  const float* wr_b[2] = {(const float*)d_in[7], (const float*)d_in[13]};
  const float* alv[2] = {(const float*)d_in[8], (const float*)d_in[14]};
  const float* arv[2] = {(const float*)d_in[9], (const float*)d_in[15]};
  const float* ww_w[2] = {(const float*)d_in[16], (const float*)d_in[18]};
  const float* ww_b[2] = {(const float*)d_in[17], (const float*)d_in[19]};
  const float* lin_w = (const float*)d_in[20];
  const float* lin_b = (const float*)d_in[21];

  char* wp = (char*)d_ws;
  auto alloc = [&](size_t b) -> char* {
    char* p = wp;
    wp += (b + 255) & ~(size_t)255;
    return p;
  };
  float* XA = (float*)alloc((size_t)NT * CD * 4);
  float* XB = (float*)alloc((size_t)NT * CD * 4);
  float* OT = (float*)alloc((size_t)NT * CD * 4);
  float* P1 = (float*)alloc((size_t)NT * CD * 4);
  float* P2 = (float*)alloc((size_t)NT * CD * 4);
  __hip_bfloat16* FBF = (__hip_bfloat16*)alloc((size_t)NT * CD * 2);
  float* CT1 = (float*)alloc(128 * 128 * 4);
  float* CT2 = (float*)alloc(128 * 128 * 4);
  float* OFF1 = (float*)alloc(128 * 128 * 4);
  float* OFF2 = (float*)alloc(128 * 128 * 4);
  float* AL = (float*)alloc(NT * 4);
  float* AR_ = (float*)alloc(NT * 4);
  float* ARS = (float*)alloc(NT * 4);
  float* Q1L = (float*)alloc(NT * 4);
  float* Q2L = (float*)alloc(NT * 4);
  float* QCT1 = (float*)alloc(128 * 4);
  float* QCT2 = (float*)alloc(128 * 4);
  float* QOF1 = (float*)alloc(128 * 4);
  float* QOF2 = (float*)alloc(128 * 4);
  float* VP = (float*)alloc(2 * 258 * 4);
  float* WT1 = (float*)alloc(256 * 128 * 4);
  float* WT2 = (float*)alloc(256 * 128 * 4);
  float* WTL = (float*)alloc(128 * 128 * 4);
  int* RANK = (int*)alloc(NT * 4);
  int* PERM = (int*)alloc(NT * 4);
  int* DEG = (int*)alloc(2 * NN * 4);
  int* OFFS = (int*)alloc(2 * (NN + 1) * 4);
  int* CURS = (int*)alloc(2 * NN * 4);
  int* ADJ = (int*)alloc(2 * NE * 4);

  k_prep<<<512, 256, 0, stream>>>(x1, x2, XA, ww_w[0], ww_w[1], lin_w, WT1, WT2, WTL,
                                  wl_w[0], wl_b[0], wr_w[0], wr_b[0], alv[0], arv[0],
                                  wl_w[1], wl_b[1], wr_w[1], wr_b[1], alv[1], arv[1],
                                  VP, DEG);
  k_s2<<<2560, 256, 0, stream>>>(ei1, ei2, DEG, XA, VP, AL, AR_, RANK);
  k_s3<<<258, 256, 0, stream>>>(DEG, OFFS, CURS, AR_, RANK);
  k_s4<<<544, 256, 0, stream>>>(ei1, ei2, CURS, ADJ, RANK, AR_, PERM, ARS);
  k_scanA<<<512, 256, 0, stream>>>(XA, PERM, ARS, RANK, P1, P2, CT1, CT2, Q1L, Q2L, QCT1, QCT2);
  k_scanB<<<1, 320, 0, stream>>>(CT1, CT2, QCT1, QCT2, OFF1, OFF2, QOF1, QOF2);
  k_combine<<<4096, 256, 0, stream>>>(XA, AL, ARS, P1, P2, OFF1, OFF2, Q1L, Q2L, QOF1, QOF2, OT);
  k_ag<<<1024, 256, 0, stream>>>(XA, OT, OFFS, ADJ, WT1, ww_b[0], XB,
                                 0, VP + 258, AL, AR_, WTL, lin_b, FBF);
  k_rank<<<256, 256, 0, stream>>>(AR_, RANK);
  k_perm<<<32, 256, 0, stream>>>(RANK, AR_, PERM, ARS);
  k_scanA<<<512, 256, 0, stream>>>(XB, PERM, ARS, RANK, P1, P2, CT1, CT2, Q1L, Q2L, QCT1, QCT2);
  k_scanB<<<1, 320, 0, stream>>>(CT1, CT2, QCT1, QCT2, OFF1, OFF2, QOF1, QOF2);
  k_combine<<<4096, 256, 0, stream>>>(XB, AL, ARS, P1, P2, OFF1, OFF2, Q1L, Q2L, QOF1, QOF2, OT);
  k_ag<<<1024, 256, 0, stream>>>(XB, OT, OFFS, ADJ, WT2, ww_b[1], XB,
                                 1, VP, AL, AR_, WTL, lin_b, FBF);
  k_final<<<dim3(64, 64), 256, 0, stream>>>((const unsigned short*)FBF, (float*)d_out);
}

// Round 22
// 266.916 us; speedup vs baseline: 1.0269x; 1.0269x over previous
//
#include <hip/hip_runtime.h>
#include <hip/hip_bf16.h>

#define NT 8192   // total nodes (2 graphs)
#define NN 4096   // nodes per graph
#define CD 128    // channels
#define NE 65536  // edges per graph

typedef __attribute__((ext_vector_type(8))) short bf16x8;
typedef __attribute__((ext_vector_type(16))) float f32x16;
typedef __attribute__((ext_vector_type(4))) float f32x4;

__device__ inline f32x4 bf4_to_f32(uint2 v) {
  f32x4 r;
  r[0] = __uint_as_float((v.x & 0xffffu) << 16);
  r[1] = __uint_as_float(v.x & 0xffff0000u);
  r[2] = __uint_as_float((v.y & 0xffffu) << 16);
  r[3] = __uint_as_float(v.y & 0xffff0000u);
  return r;
}

// ---------------- prep: concat + weight transposes + attention params + DEG zero ----------------
__global__ __launch_bounds__(256) void k_prep(
    const float* __restrict__ x1, const float* __restrict__ x2, float* __restrict__ X,
    const float* __restrict__ W1, const float* __restrict__ W2, const float* __restrict__ WL,
    float* __restrict__ WT1, float* __restrict__ WT2, float* __restrict__ WTL,
    const float* __restrict__ wlw0, const float* __restrict__ wlb0,
    const float* __restrict__ wrw0, const float* __restrict__ wrb0,
    const float* __restrict__ al0, const float* __restrict__ ar0,
    const float* __restrict__ wlw1, const float* __restrict__ wlb1,
    const float* __restrict__ wrw1, const float* __restrict__ wrb1,
    const float* __restrict__ al1, const float* __restrict__ ar1,
    float* __restrict__ VP, int* __restrict__ DEG) {
  int b = blockIdx.x, tid = threadIdx.x;
  int gid = b * 256 + tid;  // 0..131071
  {
    const f32x4* s1 = (const f32x4*)x1;
    const f32x4* s2 = (const f32x4*)x2;
    f32x4* d = (f32x4*)X;
    d[gid] = s1[gid];
    d[gid + NN * CD / 4] = s2[gid];
  }
  if (gid < 81920) {
    int idx = gid;
    if (idx < 32768) { int c = idx >> 8, k = idx & 255; WT1[k * 128 + c] = W1[idx]; }
    else if (idx < 65536) { int j = idx - 32768; int c = j >> 8, k = j & 255; WT2[k * 128 + c] = W2[j]; }
    else { int j = idx - 65536; int c = j >> 7, k = j & 127; WTL[k * 128 + c] = WL[j]; }
  }
  if ((b == 508 || b == 509) && tid < 128) {
    int L = b - 508;
    const float* wlw = L ? wlw1 : wlw0;
    const float* wlb = L ? wlb1 : wlb0;
    const float* wrw = L ? wrw1 : wrw0;
    const float* wrb = L ? wrb1 : wrb0;
    const float* alv = L ? al1 : al0;
    const float* arv = L ? ar1 : ar0;
    float* vp = VP + L * 258;
    int c = tid;
    float sl = 0.f, sr = 0.f;
    for (int h = 0; h < 128; ++h) {
      sl += wlw[h * 128 + c] * alv[h];
      sr += wrw[h * 128 + c] * arv[h];
    }
    vp[c] = sl;
    vp[128 + c] = sr;
    if (c < 2) {
      const float* bb = c ? wrb : wlb;
      const float* aa = c ? arv : alv;
      float s = 0.f;
      for (int h = 0; h < 128; ++h) s += bb[h] * aa[h];
      vp[256 + c] = s;
    }
  }
  if (gid < 2 * NN) DEG[gid] = 0;
}

// ---------------- shared bodies ----------------
__device__ inline void alar_row(const float* __restrict__ X, const float* __restrict__ VP,
                                float* __restrict__ AL, float* __restrict__ AR,
                                int row, int lane) {
  float x0 = X[row * 128 + lane], x1 = X[row * 128 + 64 + lane];
  float sl = x0 * VP[lane] + x1 * VP[64 + lane];
  float sr = x0 * VP[128 + lane] + x1 * VP[192 + lane];
  #pragma unroll
  for (int m = 1; m < 64; m <<= 1) {
    sl += __shfl_xor(sl, m, 64);
    sr += __shfl_xor(sr, m, 64);
  }
  if (lane == 0) { AL[row] = sl + VP[256]; AR[row] = sr + VP[257]; }
}

__device__ void rank_body(int rb, int tid, const float* __restrict__ AR,
                          int* __restrict__ RANK) {
  __shared__ float tile[1024];
  int jb = rb & 31, tb = rb >> 5;
  int base = tb * 1024;
  for (int t = tid; t < 1024; t += 256) tile[t] = AR[base + t];
  __syncthreads();
  int j = jb * 256 + tid;
  float aj = AR[j];
  int cnt = 0;
  #pragma unroll 8
  for (int u = 0; u < 1024; ++u) {
    float a2 = tile[u];
    cnt += (a2 < aj || (a2 == aj && (base + u) < j)) ? 1 : 0;
  }
  atomicAdd(&RANK[j], cnt);
}

__device__ void scanoff_body(int g, int tid, const int* __restrict__ DEG,
                             int* __restrict__ OFFS, int* __restrict__ CURS) {
  __shared__ int part[256];
  int loc[16];
  int s = 0;
  #pragma unroll
  for (int i = 0; i < 16; ++i) { loc[i] = s; s += DEG[g * NN + tid * 16 + i]; }
  part[tid] = s;
  __syncthreads();
  for (int d = 1; d < 256; d <<= 1) {
    int v = part[tid];
    int o = (tid >= d) ? part[tid - d] : 0;
    __syncthreads();
    part[tid] = v + o;
    __syncthreads();
  }
  int excl = tid ? part[tid - 1] : 0;
  #pragma unroll
  for (int i = 0; i < 16; ++i) {
    int o = excl + loc[i];
    OFFS[g * (NN + 1) + tid * 16 + i] = o;
    CURS[g * NN + tid * 16 + i] = o;
  }
  if (tid == 255) OFFS[g * (NN + 1) + NN] = part[255];
}

// ---------------- s2: deg atomics || alar0 (+RANK zero) ----------------
__global__ __launch_bounds__(256) void k_s2(
    const int* __restrict__ EI1, const int* __restrict__ EI2, int* __restrict__ DEG,
    const float* __restrict__ X, const float* __restrict__ VP0,
    float* __restrict__ AL, float* __restrict__ AR, int* __restrict__ RANK) {
  int b = blockIdx.x, tid = threadIdx.x;
  if (b < 512) {
    int gid = b * 256 + tid;
    int g = gid >> 16, e = gid & 65535;
    const int* src = g ? EI2 : EI1;
    atomicAdd(&DEG[g * NN + src[e]], 1);
  } else {
    int bb = b - 512;
    if (bb < 32) RANK[bb * 256 + tid] = 0;
    alar_row(X, VP0, AL, AR, bb * 4 + (tid >> 6), tid & 63);
  }
}

// ---------------- s3: scanoff || rank0 ----------------
__global__ __launch_bounds__(256) void k_s3(
    const int* __restrict__ DEG, int* __restrict__ OFFS, int* __restrict__ CURS,
    const float* __restrict__ AR, int* __restrict__ RANK) {
  int b = blockIdx.x, tid = threadIdx.x;
  if (b < 2) scanoff_body(b, tid, DEG, OFFS, CURS);
  else rank_body(b - 2, tid, AR, RANK);
}

// ---------------- s4: fill || perm0 ----------------
__global__ __launch_bounds__(256) void k_s4(
    const int* __restrict__ EI1, const int* __restrict__ EI2,
    int* __restrict__ CURS, int* __restrict__ ADJ,
    const int* __restrict__ RANK, const float* __restrict__ AR,
    int* __restrict__ PERM, float* __restrict__ ARS) {
  int b = blockIdx.x, tid = threadIdx.x;
  if (b < 512) {
    int gid = b * 256 + tid;
    int g = gid >> 16, e = gid & 65535;
    const int* ei = g ? EI2 : EI1;
    int s = ei[e], d = ei[NE + e];
    int pos = atomicAdd(&CURS[g * NN + s], 1);
    ADJ[g * NE + pos] = d;
  } else {
    int j = (b - 512) * 256 + tid;
    int r = RANK[j];
    PERM[r] = j;
    ARS[r] = AR[j];
  }
}

// plain rank (layer 1) and perm (layer 1)
__global__ void k_rank(const float* __restrict__ AR, int* __restrict__ RANK) {
  rank_body(blockIdx.x, threadIdx.x, AR, RANK);
}
__global__ void k_perm(const int* __restrict__ RANK, const float* __restrict__ AR,
                       int* __restrict__ PERM, float* __restrict__ ARS) {
  int j = blockIdx.x * 256 + threadIdx.x;
  int r = RANK[j];
  PERM[r] = j;
  ARS[r] = AR[j];
}

// hierarchical prefix sums, 4-way t-split (512 blocks); blocks<32 zero RANK for next rank pass
__global__ __launch_bounds__(256) void k_scanA(
    const float* __restrict__ X, const int* __restrict__ PERM,
    const float* __restrict__ ARS, int* __restrict__ RANK,
    float* __restrict__ P1, float* __restrict__ P2,
    float* __restrict__ CT1, float* __restrict__ CT2,
    float* __restrict__ Q1L, float* __restrict__ Q2L,
    float* __restrict__ QCT1, float* __restrict__ QCT2) {
  __shared__ int pc[64];
  __shared__ float w[2][64];
  __shared__ float part[2][4][32];
  __shared__ float qpart[2][4];
  int b = blockIdx.x;
  if (b < 32) RANK[b * 256 + threadIdx.x] = 0;
  int chunk = b >> 2, sub = b & 3;
  int tid = threadIdx.x;
  int a = tid >> 7;
  int g = (tid >> 5) & 3;
  int cl = tid & 31;
  int c = sub * 32 + cl;
  if (tid < 64) {
    int r = chunk * 64 + tid;
    pc[tid] = PERM[r];
    float ar = ARS[r];
    w[0][tid] = __expf(ar);
    w[1][tid] = __expf(0.2f * ar);
  }
  __syncthreads();
  int t0 = g * 16;
  float loc[16];
  float acc = 0.f;
  #pragma unroll 4
  for (int t = 0; t < 16; ++t) {
    acc += w[a][t0 + t] * X[pc[t0 + t] * 128 + c];
    loc[t] = acc;
  }
  part[a][g][cl] = acc;
  float qloc[16];
  float qacc = 0.f;
  bool doQ = (sub == 0 && cl == 0);
  if (doQ) {
    for (int t = 0; t < 16; ++t) { qacc += w[a][t0 + t]; qloc[t] = qacc; }
    qpart[a][g] = qacc;
  }
  __syncthreads();
  float off = (g > 0 ? part[a][0][cl] : 0.f) + (g > 1 ? part[a][1][cl] : 0.f) +
              (g > 2 ? part[a][2][cl] : 0.f);
  float* P = a ? P2 : P1;
  #pragma unroll 4
  for (int t = 0; t < 16; ++t) P[(chunk * 64 + t0 + t) * 128 + c] = loc[t] + off;
  if (g == 3) (a ? CT2 : CT1)[chunk * 128 + c] = off + acc;
  if (doQ) {
    float qoff = (g > 0 ? qpart[a][0] : 0.f) + (g > 1 ? qpart[a][1] : 0.f) +
                 (g > 2 ? qpart[a][2] : 0.f);
    float* Q = a ? Q2L : Q1L;
    for (int t = 0; t < 16; ++t) Q[chunk * 64 + t0 + t] = qloc[t] + qoff;
    if (g == 3) (a ? QCT2 : QCT1)[chunk] = qoff + qacc;
  }
}

__global__ __launch_bounds__(320) void k_scanB(
    const float* __restrict__ CT1, const float* __restrict__ CT2,
    const float* __restrict__ QCT1, const float* __restrict__ QCT2,
    float* __restrict__ OFF1, float* __restrict__ OFF2,
    float* __restrict__ QOF1, float* __restrict__ QOF2) {
  int tid = threadIdx.x;
  if (tid < 128) {
    float acc = 0.f;
    #pragma unroll 8
    for (int ch = 0; ch < 128; ++ch) { acc += CT1[ch * 128 + tid]; OFF1[ch * 128 + tid] = acc; }
  } else if (tid < 256) {
    int c = tid - 128;
    float acc = 0.f;
    #pragma unroll 8
    for (int ch = 0; ch < 128; ++ch) { acc += CT2[ch * 128 + c]; OFF2[ch * 128 + c] = acc; }
  } else if (tid == 256) {
    float acc = 0.f;
    for (int ch = 0; ch < 128; ++ch) { acc += QCT1[ch]; QOF1[ch] = acc; }
  } else if (tid == 257) {
    float acc = 0.f;
    for (int ch = 0; ch < 128; ++ch) { acc += QCT2[ch]; QOF2[ch] = acc; }
  }
}

// ot combine -> packed bf16 gather rows G[row][256] = [bf16(x) | bf16(ot)]
__global__ void k_combine(const float* __restrict__ X, const float* __restrict__ AL,
                          const float* __restrict__ ARS,
                          const float* __restrict__ P1, const float* __restrict__ P2,
                          const float* __restrict__ OFF1, const float* __restrict__ OFF2,
                          const float* __restrict__ Q1L, const float* __restrict__ Q2L,
                          const float* __restrict__ QOF1, const float* __restrict__ QOF2,
                          __hip_bfloat16* __restrict__ G) {
  int row = blockIdx.x * 2 + (threadIdx.x >> 7);
  int c = threadIdx.x & 127;
  float ali = AL[row];
  float A1 = __expf(ali), A2 = __expf(0.2f * ali);
  float xv = -ali;
  int lo = 0, hi = NT;
  while (lo < hi) {
    int mid = (lo + hi) >> 1;
    if (ARS[mid] <= xv) lo = mid + 1; else hi = mid;
  }
  int b = lo - 1;
  float p1 = 0.f, p2 = 0.f, q1 = 0.f, q2 = 0.f;
  if (b >= 0) {
    int ch = b >> 6;
    p1 = P1[b * 128 + c] + (ch ? OFF1[(ch - 1) * 128 + c] : 0.f);
    p2 = P2[b * 128 + c] + (ch ? OFF2[(ch - 1) * 128 + c] : 0.f);
    q1 = Q1L[b] + (ch ? QOF1[ch - 1] : 0.f);
    q2 = Q2L[b] + (ch ? QOF2[ch - 1] : 0.f);
  }
  float T1 = OFF1[127 * 128 + c];
  float QT1 = QOF1[127];
  float num = A1 * (T1 - p1) + A2 * p2;
  float den = A1 * (QT1 - q1) + A2 * q2;
  float x = X[row * 128 + c];
  G[(size_t)row * 256 + c] = __float2bfloat16(x);
  G[(size_t)row * 256 + 128 + c] = __float2bfloat16(x - num / den);
}

// ---------------- fused: CSR-mean gather (bf16 rows, LDS indices, 4-deep ILP) + relu + GEMM ----------------
__global__ __launch_bounds__(256, 4) void k_ag(
    const __hip_bfloat16* __restrict__ G,
    const int* __restrict__ OFFS, const int* __restrict__ ADJ,
    const float* __restrict__ WT, const float* __restrict__ WB, float* __restrict__ XN,
    int mode,  // 0: + alar(next layer) ; 1: + lin -> FBF
    const float* __restrict__ VP1, float* __restrict__ AL, float* __restrict__ AR,
    const float* __restrict__ WTL, const float* __restrict__ LINB,
    __hip_bfloat16* __restrict__ FBF) {
  __shared__ float sA[8 * 256];
  __shared__ float sB[8 * 128];
  __shared__ int sOff[9];
  __shared__ int sIdx[1024];
  int b = blockIdx.x, tid = threadIdx.x;
  int lane = tid & 63, wv = tid >> 6;
  int g = b >> 9;
  int n0 = (b * 8) & (NN - 1);
  if (tid < 9) sOff[tid] = OFFS[g * (NN + 1) + n0 + tid];
  __syncthreads();
  int begAll = sOff[0], cnt = sOff[8] - begAll;
  const int* adjg = ADJ + g * NE + begAll;
  for (int t = tid; t < cnt; t += 256) sIdx[t] = adjg[t];
  __syncthreads();
  {
    // lane covers channels lane*4..lane*4+3 of the 256-wide packed row
    const uint2* gb = (const uint2*)G + ((size_t)(g * NN) << 6);
    #pragma unroll
    for (int k = 0; k < 2; ++k) {
      int ln = wv * 2 + k;
      int e0 = sOff[ln] - begAll, e1 = sOff[ln + 1] - begAll;
      f32x4 p0 = bf4_to_f32(gb[(size_t)(n0 + ln) * 64 + lane]);  // self loop
      f32x4 p1 = {0.f, 0.f, 0.f, 0.f}, p2 = p1, p3 = p1;
      int j = e0;
      for (; j + 4 <= e1; j += 4) {
        int i0 = sIdx[j], i1 = sIdx[j + 1], i2 = sIdx[j + 2], i3 = sIdx[j + 3];
        uint2 v0 = gb[(size_t)i0 * 64 + lane];
        uint2 v1 = gb[(size_t)i1 * 64 + lane];
        uint2 v2 = gb[(size_t)i2 * 64 + lane];
        uint2 v3 = gb[(size_t)i3 * 64 + lane];
        p0 += bf4_to_f32(v0);
        p1 += bf4_to_f32(v1);
        p2 += bf4_to_f32(v2);
        p3 += bf4_to_f32(v3);
      }
      for (; j < e1; ++j) p1 += bf4_to_f32(gb[(size_t)sIdx[j] * 64 + lane]);
      f32x4 r = (p0 + p1) + (p2 + p3);
      r /= (float)(e1 - e0 + 1);
      #pragma unroll
      for (int q = 0; q < 4; ++q) r[q] = fmaxf(r[q], 0.f);
      *(f32x4*)&sA[ln * 256 + lane * 4] = r;
    }
  }
  __syncthreads();
  int c = tid & 127, half = tid >> 7;
  float accv[4];
  float bc = WB[c];
  #pragma unroll
  for (int i = 0; i < 4; ++i) accv[i] = bc;
  for (int k4 = 0; k4 < 64; ++k4) {
    float w0 = WT[(k4 * 4 + 0) * 128 + c];
    float w1v = WT[(k4 * 4 + 1) * 128 + c];
    float w2v = WT[(k4 * 4 + 2) * 128 + c];
    float w3 = WT[(k4 * 4 + 3) * 128 + c];
    #pragma unroll
    for (int i = 0; i < 4; ++i) {
      f32x4 av = *(const f32x4*)&sA[(half * 4 + i) * 256 + k4 * 4];
      accv[i] += av[0] * w0 + av[1] * w1v + av[2] * w2v + av[3] * w3;
    }
  }
  #pragma unroll
  for (int i = 0; i < 4; ++i) {
    sB[(half * 4 + i) * 128 + c] = accv[i];
    if (mode == 0) XN[(size_t)(b * 8 + half * 4 + i) * 128 + c] = accv[i];
  }
  __syncthreads();
  if (mode == 0) {
    #pragma unroll
    for (int k = 0; k < 2; ++k) {
      int lr = wv * 2 + k;
      float x0 = sB[lr * 128 + lane], x1 = sB[lr * 128 + 64 + lane];
      float sl = x0 * VP1[lane] + x1 * VP1[64 + lane];
      float sr = x0 * VP1[128 + lane] + x1 * VP1[192 + lane];
      #pragma unroll
      for (int m = 1; m < 64; m <<= 1) {
        sl += __shfl_xor(sl, m, 64);
        sr += __shfl_xor(sr, m, 64);
      }
      if (lane == 0) { AL[b * 8 + lr] = sl + VP1[256]; AR[b * 8 + lr] = sr + VP1[257]; }
    }
  } else {
    float acl[4];
    float lb = LINB[c];
    #pragma unroll
    for (int i = 0; i < 4; ++i) acl[i] = lb;
    for (int k4 = 0; k4 < 32; ++k4) {
      float w0 = WTL[(k4 * 4 + 0) * 128 + c];
      float w1v = WTL[(k4 * 4 + 1) * 128 + c];
      float w2v = WTL[(k4 * 4 + 2) * 128 + c];
      float w3 = WTL[(k4 * 4 + 3) * 128 + c];
      #pragma unroll
      for (int i = 0; i < 4; ++i) {
        f32x4 av = *(const f32x4*)&sB[(half * 4 + i) * 128 + k4 * 4];
        acl[i] += av[0] * w0 + av[1] * w1v + av[2] * w2v + av[3] * w3;
      }
    }
    #pragma unroll
    for (int i = 0; i < 4; ++i)
      FBF[(size_t)(b * 8 + half * 4 + i) * 128 + c] = __float2bfloat16(acl[i]);
  }
}

// ---------------- final: out = sigmoid(F F^T), F bf16 8192x128 ----------------
__device__ inline f32x16 zero16() {
  f32x16 v;
  #pragma unroll
  for (int i = 0; i < 16; ++i) v[i] = 0.f;
  return v;
}

__device__ inline float sigf(float v) {
  return __builtin_amdgcn_rcpf(1.f + __expf(-v));
}

__global__ __launch_bounds__(256) void k_final(const unsigned short* __restrict__ F,
                                               float* __restrict__ out) {
  __shared__ __align__(16) char smem[65536];
  unsigned short* AT = (unsigned short*)smem;
  unsigned short* BT = AT + 16384;
  int cb = blockIdx.x, rb = blockIdx.y;
  int tid = threadIdx.x;
  #pragma unroll
  for (int q = 0; q < 8; ++q) {
    int idx = q * 256 + tid;
    int r = idx >> 4, ck = idx & 15;
    unsigned off = (unsigned)((r * 256 + ck * 16) ^ ((r & 7) << 4));
    uint4 va = *(const uint4*)(F + (size_t)(rb * 128 + r) * 128 + ck * 8);
    *(uint4*)((char*)AT + off) = va;
    uint4 vb = *(const uint4*)(F + (size_t)(cb * 128 + r) * 128 + ck * 8);
    *(uint4*)((char*)BT + off) = vb;
  }
  __syncthreads();
  int lane = tid & 63, w = tid >> 6;
  int wr = w >> 1, wc = w & 1;
  int l31 = lane & 31, kh = lane >> 5;
  int xorm = (l31 & 7) << 4;
  int rowA0 = wr * 64 + l31, rowA1 = rowA0 + 32;
  int rowB0 = wc * 64 + l31, rowB1 = rowB0 + 32;
  f32x16 a00 = zero16(), a01 = zero16(), a10 = zero16(), a11 = zero16();
  #pragma unroll
  for (int ks = 0; ks < 8; ++ks) {
    int kb = ks * 32 + kh * 16;
    bf16x8 av0 = *(const bf16x8*)((const char*)AT + ((rowA0 * 256 + kb) ^ xorm));
    bf16x8 av1 = *(const bf16x8*)((const char*)AT + ((rowA1 * 256 + kb) ^ xorm));
    bf16x8 bv0 = *(const bf16x8*)((const char*)BT + ((rowB0 * 256 + kb) ^ xorm));
    bf16x8 bv1 = *(const bf16x8*)((const char*)BT + ((rowB1 * 256 + kb) ^ xorm));
    a00 = __builtin_amdgcn_mfma_f32_32x32x16_bf16(av0, bv0, a00, 0, 0, 0);
    a01 = __builtin_amdgcn_mfma_f32_32x32x16_bf16(av0, bv1, a01, 0, 0, 0);
    a10 = __builtin_amdgcn_mfma_f32_32x32x16_bf16(av1, bv0, a10, 0, 0, 0);
    a11 = __builtin_amdgcn_mfma_f32_32x32x16_bf16(av1, bv1, a11, 0, 0, 0);
  }
  __syncthreads();
  float* lw = (float*)smem + w * 4096;
  #pragma unroll
  for (int r = 0; r < 16; ++r) {
    int rl = (r & 3) + 8 * (r >> 2) + 4 * kh;
    lw[rl * 64 + l31] = sigf(a00[r]);
    lw[rl * 64 + l31 + 32] = sigf(a01[r]);
    lw[(rl + 32) * 64 + l31] = sigf(a10[r]);
    lw[(rl + 32) * 64 + l31 + 32] = sigf(a11[r]);
  }
  int grb = rb * 128 + wr * 64, gcb = cb * 128 + wc * 64;
  #pragma unroll
  for (int j = 0; j < 16; ++j) {
    int row = j * 4 + (lane >> 4);
    int c4 = (lane & 15) * 4;
    f32x4 v = *(const f32x4*)&lw[row * 64 + c4];
    *(f32x4*)&out[(size_t)(grb + row) * 8192 + gcb + c4] = v;
  }
}

// ---------------- host ----------------
extern "C" void kernel_launch(void* const* d_in, const int* in_sizes, int n_in,
                              void* d_out, int out_size, void* d_ws, size_t ws_size,
                              hipStream_t stream) {
  (void)in_sizes; (void)n_in; (void)out_size; (void)ws_size;
  const float* x1 = (const float*)d_in[0];
  const float* x2 = (const float*)d_in[1];
  const int* ei1 = (const int*)d_in[2];
  const int* ei2 = (const int*)d_in[3];
  const float* wl_w[2] = {(const float*)d_in[4], (const float*)d_in[10]};
  const float* wl_b[2] = {(const float*)d_in[5], (const float*)d_in[11]};
  const float* wr_w[2] = {(const float*)d_in[6], (const float*)d_in[12]};
  const float* wr_b[2] = {(const float*)d_in[7], (const float*)d_in[13]};
  const float* alv[2] = {(const float*)d_in[8], (const float*)d_in[14]};
  const float* arv[2] = {(const float*)d_in[9], (const float*)d_in[15]};
  const float* ww_w[2] = {(const float*)d_in[16], (const float*)d_in[18]};
  const float* ww_b[2] = {(const float*)d_in[17], (const float*)d_in[19]};
  const float* lin_w = (const float*)d_in[20];
  const float* lin_b = (const float*)d_in[21];

  char* wp = (char*)d_ws;
  auto alloc = [&](size_t b) -> char* {
    char* p = wp;
    wp += (b + 255) & ~(size_t)255;
    return p;
  };
  float* XA = (float*)alloc((size_t)NT * CD * 4);
  float* XB = (float*)alloc((size_t)NT * CD * 4);
  __hip_bfloat16* G = (__hip_bfloat16*)alloc((size_t)NT * 256 * 2);  // packed [x|ot] bf16
  float* P1 = (float*)alloc((size_t)NT * CD * 4);
  float* P2 = (float*)alloc((size_t)NT * CD * 4);
  __hip_bfloat16* FBF = (__hip_bfloat16*)alloc((size_t)NT * CD * 2);
  float* CT1 = (float*)alloc(128 * 128 * 4);
  float* CT2 = (float*)alloc(128 * 128 * 4);
  float* OFF1 = (float*)alloc(128 * 128 * 4);
  float* OFF2 = (float*)alloc(128 * 128 * 4);
  float* AL = (float*)alloc(NT * 4);
  float* AR_ = (float*)alloc(NT * 4);
  float* ARS = (float*)alloc(NT * 4);
  float* Q1L = (float*)alloc(NT * 4);
  float* Q2L = (float*)alloc(NT * 4);
  float* QCT1 = (float*)alloc(128 * 4);
  float* QCT2 = (float*)alloc(128 * 4);
  float* QOF1 = (float*)alloc(128 * 4);
  float* QOF2 = (float*)alloc(128 * 4);
  float* VP = (float*)alloc(2 * 258 * 4);
  float* WT1 = (float*)alloc(256 * 128 * 4);
  float* WT2 = (float*)alloc(256 * 128 * 4);
  float* WTL = (float*)alloc(128 * 128 * 4);
  int* RANK = (int*)alloc(NT * 4);
  int* PERM = (int*)alloc(NT * 4);
  int* DEG = (int*)alloc(2 * NN * 4);
  int* OFFS = (int*)alloc(2 * (NN + 1) * 4);
  int* CURS = (int*)alloc(2 * NN * 4);
  int* ADJ = (int*)alloc(2 * NE * 4);

  k_prep<<<512, 256, 0, stream>>>(x1, x2, XA, ww_w[0], ww_w[1], lin_w, WT1, WT2, WTL,
                                  wl_w[0], wl_b[0], wr_w[0], wr_b[0], alv[0], arv[0],
                                  wl_w[1], wl_b[1], wr_w[1], wr_b[1], alv[1], arv[1],
                                  VP, DEG);
  k_s2<<<2560, 256, 0, stream>>>(ei1, ei2, DEG, XA, VP, AL, AR_, RANK);
  k_s3<<<258, 256, 0, stream>>>(DEG, OFFS, CURS, AR_, RANK);
  k_s4<<<544, 256, 0, stream>>>(ei1, ei2, CURS, ADJ, RANK, AR_, PERM, ARS);
  k_scanA<<<512, 256, 0, stream>>>(XA, PERM, ARS, RANK, P1, P2, CT1, CT2, Q1L, Q2L, QCT1, QCT2);
  k_scanB<<<1, 320, 0, stream>>>(CT1, CT2, QCT1, QCT2, OFF1, OFF2, QOF1, QOF2);
  k_combine<<<4096, 256, 0, stream>>>(XA, AL, ARS, P1, P2, OFF1, OFF2, Q1L, Q2L, QOF1, QOF2, G);
  k_ag<<<1024, 256, 0, stream>>>(G, OFFS, ADJ, WT1, ww_b[0], XB,
                                 0, VP + 258, AL, AR_, WTL, lin_b, FBF);
  k_rank<<<256, 256, 0, stream>>>(AR_, RANK);
  k_perm<<<32, 256, 0, stream>>>(RANK, AR_, PERM, ARS);
  k_scanA<<<512, 256, 0, stream>>>(XB, PERM, ARS, RANK, P1, P2, CT1, CT2, Q1L, Q2L, QCT1, QCT2);
  k_scanB<<<1, 320, 0, stream>>>(CT1, CT2, QCT1, QCT2, OFF1, OFF2, QOF1, QOF2);
  k_combine<<<4096, 256, 0, stream>>>(XB, AL, ARS, P1, P2, OFF1, OFF2, Q1L, Q2L, QOF1, QOF2, G);
  k_ag<<<1024, 256, 0, stream>>>(G, OFFS, ADJ, WT2, ww_b[1], XB,
                                 1, VP, AL, AR_, WTL, lin_b, FBF);
  k_final<<<dim3(64, 64), 256, 0, stream>>>((const unsigned short*)FBF, (float*)d_out);
}